// Round 17
// baseline (314.675 us; speedup 1.0000x reference)
//
#include <hip/hip_runtime.h>
#include <hip/hip_bf16.h>

// QLoRA forward: out = x @ dequant(q_w, scales)^T + 2.0 * (x @ A^T) @ B^T
// M=8192, N=4096, K=4096, rank=16, group=64.
// Round 17: r16 base + split-mfma1 reorder. mfma1's first half (i=0..3) runs
// BEFORE the vmcnt(0)+barrier (it needs only registers), growing the stage
// drain's MFMA cover 1242->~1860cyc (straggler stall); second half stays
// after the barrier to cover read0(nb)'s LDS burst. Prologue stages tiles
// 0 AND 1 so body 0's drain is long-covered. All sync guarantees unchanged.

typedef unsigned short u16;
typedef __attribute__((ext_vector_type(8))) short bf16x8;
typedef __attribute__((ext_vector_type(4))) float f32x4;
typedef __attribute__((ext_vector_type(4))) int i32x4;

#define M_DIM 8192
#define N_DIM 4096
#define K_DIM 4096
#define BK 64
#define KT_MAIN 64
#define NT 65

// round-to-nearest-even f32 -> bf16
__device__ static inline u16 f2bf(float f) {
    union { float f; unsigned u; } v; v.f = f;
    unsigned r = v.u + 0x7fffu + ((v.u >> 16) & 1u);
    return (u16)(r >> 16);
}

__device__ static inline void gload16(const void* g, void* s) {
    __builtin_amdgcn_global_load_lds(
        (const __attribute__((address_space(1))) void*)g,
        (__attribute__((address_space(3))) void*)s, 16, 0, 0);
}

// ---------------- fused prep (r13/r16 layout) -------------------------------
// blocks 0..1023: xprep (2 rows/wave); 1024..9215: wprep; 9216..10239: bprep.
// t2 [8192][64] bf16 (cols 16..63 = 0); B2 [4096][64] (cols 16..63 = 0).
__global__ __launch_bounds__(256) void prep_kernel(
        const int* __restrict__ q, const float* __restrict__ scales,
        const float* __restrict__ lora_B, const float* __restrict__ x,
        const float* __restrict__ lora_A,
        u16* __restrict__ Wb, u16* __restrict__ B2,
        u16* __restrict__ xb, u16* __restrict__ t2) {
    const int tid = threadIdx.x;
    int b = blockIdx.x;
    if (b < 1024) {
        // ---- xprep: xb = bf16(x); t2 = bf16(2 * x @ A^T), [8192][64] ----
        const int w = tid >> 6, l = tid & 63;
        const int rb = b * 8 + w * 2;
        float acc[2][16];
#pragma unroll
        for (int j = 0; j < 2; ++j)
#pragma unroll
            for (int r = 0; r < 16; ++r) acc[j][r] = 0.f;

        for (int i = 0; i < 16; ++i) {
            int k0 = i * 256 + l * 4;
            f32x4 x0 = __builtin_nontemporal_load(
                            (const f32x4*)&x[(size_t)rb * K_DIM + k0]);
            f32x4 x1 = __builtin_nontemporal_load(
                            (const f32x4*)&x[(size_t)(rb + 1) * K_DIM + k0]);
            ushort4 o0, o1;
            o0.x = f2bf(x0.x); o0.y = f2bf(x0.y); o0.z = f2bf(x0.z); o0.w = f2bf(x0.w);
            o1.x = f2bf(x1.x); o1.y = f2bf(x1.y); o1.z = f2bf(x1.z); o1.w = f2bf(x1.w);
            *(ushort4*)&xb[(size_t)rb * K_DIM + k0]       = o0;
            *(ushort4*)&xb[(size_t)(rb + 1) * K_DIM + k0] = o1;
#pragma unroll
            for (int r = 0; r < 16; ++r) {
                f32x4 av = *(const f32x4*)&lora_A[(size_t)r * K_DIM + k0];
                acc[0][r] += x0.x * av.x + x0.y * av.y + x0.z * av.z + x0.w * av.w;
                acc[1][r] += x1.x * av.x + x1.y * av.y + x1.z * av.z + x1.w * av.w;
            }
        }
#pragma unroll
        for (int j = 0; j < 2; ++j)
#pragma unroll
            for (int r = 0; r < 16; ++r) {
                float v = acc[j][r];
                v += __shfl_xor(v, 32); v += __shfl_xor(v, 16);
                v += __shfl_xor(v, 8);  v += __shfl_xor(v, 4);
                v += __shfl_xor(v, 2);  v += __shfl_xor(v, 1);
                acc[j][r] = v;
            }
        // lane l -> row rb+(l>>5), col pair (l&31): pack 2 bf16 per dword.
        float lo = 0.f, hi = 0.f;
#pragma unroll
        for (int j = 0; j < 2; ++j)
#pragma unroll
            for (int c = 0; c < 8; ++c)
                if (l == j * 32 + c) { lo = acc[j][2 * c]; hi = acc[j][2 * c + 1]; }
        unsigned pack = (unsigned)f2bf(2.0f * lo) | ((unsigned)f2bf(2.0f * hi) << 16);
        *(unsigned*)&t2[(size_t)(rb + (l >> 5)) * 64 + (l & 31) * 2] = pack;
    } else if (b < 9216) {
        // ---- wprep: Wb[o][k] = bf16(q[o][k] * scales[o][k/64]) ----
        int idx = (b - 1024) * 256 + tid;
        int o  = idx >> 9;
        int kc = (idx & 511) << 3;
        float s = scales[(o << 6) + (kc >> 6)];
        const i32x4* qp = (const i32x4*)(q + (size_t)o * K_DIM + kc);
        i32x4 q0 = __builtin_nontemporal_load(qp);
        i32x4 q1 = __builtin_nontemporal_load(qp + 1);
        ushort4 r0, r1;
        r0.x = f2bf((float)q0.x * s); r0.y = f2bf((float)q0.y * s);
        r0.z = f2bf((float)q0.z * s); r0.w = f2bf((float)q0.w * s);
        r1.x = f2bf((float)q1.x * s); r1.y = f2bf((float)q1.y * s);
        r1.z = f2bf((float)q1.z * s); r1.w = f2bf((float)q1.w * s);
        *(ushort4*)&Wb[(size_t)o * K_DIM + kc]     = r0;
        *(ushort4*)&Wb[(size_t)o * K_DIM + kc + 4] = r1;
    } else {
        // ---- bprep: B2 [4096][64], cols 16..63 = 0 ----
        int idx = (b - 9216) * 256 + tid;   // 1024 blocks -> 4096*64
        int o = idx >> 6, r = idx & 63;
        B2[idx] = (r < 16) ? f2bf(lora_B[o * 16 + r]) : (u16)0;
    }
}

// ---------------- main GEMM ------------------------------------------------
// 256x256 tile, BK=64, 8 waves (2x4), LDS 2 bufs x (A 32KB + B 32KB) = 128KB.
// Row = 128B = 8 slots of 16B. Swizzle: phys slot p of row r holds logical
// slot p ^ (r&7); achieved by pre-swizzling the gload SOURCE (dest linear).
__global__ __launch_bounds__(512, 2) void qlora_gemm(
        const u16* __restrict__ xb, const u16* __restrict__ Wb,
        const u16* __restrict__ t2, const u16* __restrict__ B2,
        float* __restrict__ out) {
    __shared__ u16 lds[2][32768];                 // 128 KB
    // XCD map: XCD x owns 16bm x 4bn rectangle (bijective, 512 = 8*64).
    int bid = blockIdx.x;
    int x8 = bid & 7, sq = bid >> 3;
    int bm = (x8 & 1) * 16 + (sq & 15);           // 0..31
    int bn = (x8 >> 1) * 4 + (sq >> 4);           // 0..15
    const int tid = threadIdx.x, w = tid >> 6, l = tid & 63;
    const int wr = w >> 2, wc = w & 3;            // 2x4 wave grid, 128x64/wave
    const int fr = l & 15, fq = l >> 4;
    const int s0 = fq ^ (fr & 7);                 // swizzled slot, kk=0 (kk1: ^4)

    const int sw16 = ((l & 7) ^ ((l >> 3) & 7)) << 4;   // pre-swizzled src offset
    const int rl   = w * 8 + (l >> 3);
    const int rA0  = bm * 256 + rl;
    const int rB0  = bn * 256 + rl;
    char* ldsC = (char*)&lds[0][0];
    const int dst = w * 1024 + l * 16;            // + o*8192 (A), +32768 (B)

    const int arow = (wr * 128 + fr) * 128;              // + i*2048 + slot*16
    const int brow = 32768 + (wc * 64 + fr) * 128;       // + j*2048 + slot*16

    f32x4 acc[8][4] = {};
    bf16x8 a0[8], b0[4], a1[8], b1[4];

    auto stage = [&](int kt, int buf) {           // 8 gloads: full 64KB tile
        char* base = ldsC + buf * 65536;
        if (kt < KT_MAIN) {
            size_t ko = (size_t)kt * 128;
#pragma unroll
            for (int o = 0; o < 4; ++o) {
                gload16((const char*)xb + ((size_t)(rA0 + o * 64) * 8192 + sw16) + ko,
                        base + dst + o * 8192);
                gload16((const char*)Wb + ((size_t)(rB0 + o * 64) * 8192 + sw16) + ko,
                        base + 32768 + dst + o * 8192);
            }
        } else {                                  // lora tile: 128B rows
#pragma unroll
            for (int o = 0; o < 4; ++o) {
                gload16((const char*)t2 + ((size_t)(rA0 + o * 64) * 128 + sw16),
                        base + dst + o * 8192);
                gload16((const char*)B2 + ((size_t)(rB0 + o * 64) * 128 + sw16),
                        base + 32768 + dst + o * 8192);
            }
        }
    };

    auto read0 = [&](const char* cb) {
#pragma unroll
        for (int j = 0; j < 4; ++j)
            b0[j] = *(const bf16x8*)(cb + brow + j * 2048 + s0 * 16);
#pragma unroll
        for (int i = 0; i < 8; ++i)
            a0[i] = *(const bf16x8*)(cb + arow + i * 2048 + s0 * 16);
    };
    auto read1 = [&](const char* cb) {
#pragma unroll
        for (int j = 0; j < 4; ++j)
            b1[j] = *(const bf16x8*)(cb + brow + j * 2048 + (s0 ^ 4) * 16);
#pragma unroll
        for (int i = 0; i < 8; ++i)
            a1[i] = *(const bf16x8*)(cb + arow + i * 2048 + (s0 ^ 4) * 16);
    };
    auto mfma0 = [&]() {
        __builtin_amdgcn_s_setprio(1);
#pragma unroll
        for (int i = 0; i < 8; ++i)
#pragma unroll
            for (int j = 0; j < 4; ++j)
                acc[i][j] = __builtin_amdgcn_mfma_f32_16x16x32_bf16(
                                a0[i], b0[j], acc[i][j], 0, 0, 0);
        __builtin_amdgcn_s_setprio(0);
    };
    auto mfma1a = [&]() {                          // kk1, C rows 0..63
        __builtin_amdgcn_s_setprio(1);
#pragma unroll
        for (int i = 0; i < 4; ++i)
#pragma unroll
            for (int j = 0; j < 4; ++j)
                acc[i][j] = __builtin_amdgcn_mfma_f32_16x16x32_bf16(
                                a1[i], b1[j], acc[i][j], 0, 0, 0);
        __builtin_amdgcn_s_setprio(0);
    };
    auto mfma1b = [&]() {                          // kk1, C rows 64..127
        __builtin_amdgcn_s_setprio(1);
#pragma unroll
        for (int i = 4; i < 8; ++i)
#pragma unroll
            for (int j = 0; j < 4; ++j)
                acc[i][j] = __builtin_amdgcn_mfma_f32_16x16x32_bf16(
                                a1[i], b1[j], acc[i][j], 0, 0, 0);
        __builtin_amdgcn_s_setprio(0);
    };

    // ---------------- prologue: stage tiles 0 AND 1 ----------------
    stage(0, 0);
    stage(1, 1);
    asm volatile("s_waitcnt vmcnt(8)" ::: "memory");   // tile 0 landed
    __builtin_amdgcn_s_barrier();
    asm volatile("" ::: "memory");

    read0(ldsC);

    for (int t = 0; t < NT; ++t) {
        const char* cb = ldsC + (t & 1) * 65536;

        // (1) kk1 frag reads — drain under mfma0
        read1(cb);
        // (2) next-tile staging (tile t+1; t=0's was staged in prologue)
        if (t >= 1 && t + 1 < NT) stage(t + 1, (t + 1) & 1);
        __builtin_amdgcn_sched_barrier(0);

        // (3) MFMA kk0 (a0/b0 long-landed)
        mfma0();
        __builtin_amdgcn_sched_barrier(0);

        // (4) read1 drained (covered by mfma0); then kk1 FIRST half —
        //     registers only, extends the stage-drain cover
        asm volatile("s_waitcnt lgkmcnt(0)" ::: "memory");
        __builtin_amdgcn_sched_barrier(0);
        mfma1a();
        __builtin_amdgcn_sched_barrier(0);

        // (5) protocol: next tile fully staged, then rendezvous
        asm volatile("s_waitcnt vmcnt(0)" ::: "memory");
        __builtin_amdgcn_s_barrier();
        asm volatile("" ::: "memory");

        // (6) next-tile kk0 frag reads — drain under kk1 second half
        if (t + 1 < NT) {
            const char* nb = ldsC + ((t + 1) & 1) * 65536;
            read0(nb);
        }
        __builtin_amdgcn_sched_barrier(0);

        // (7) MFMA kk1 second half
        mfma1b();
        __builtin_amdgcn_sched_barrier(0);
    }

    // epilogue: C/D layout col=lane&15, row=(lane>>4)*4+reg  [validated]
    float* obase = out + (size_t)(bm * 256 + wr * 128 + fq * 4) * N_DIM
                       + bn * 256 + wc * 64 + fr;
#pragma unroll
    for (int i = 0; i < 8; ++i)
#pragma unroll
        for (int j = 0; j < 4; ++j)
#pragma unroll
            for (int r = 0; r < 4; ++r)
                obase[(size_t)(i * 16 + r) * N_DIM + j * 16] = acc[i][j][r];
}

extern "C" void kernel_launch(void* const* d_in, const int* in_sizes, int n_in,
                              void* d_out, int out_size, void* d_ws, size_t ws_size,
                              hipStream_t stream) {
    const float* x      = (const float*)d_in[0];
    const int*   qw     = (const int*)d_in[1];
    const float* scales = (const float*)d_in[2];
    const float* lora_A = (const float*)d_in[3];
    const float* lora_B = (const float*)d_in[4];
    float* out = (float*)d_out;

    char* ws = (char*)d_ws;
    u16* xb = (u16*)(ws);                       // 8192*4096*2 = 67,108,864 B
    u16* Wb = (u16*)(ws + 67108864);            // 4096*4096*2 = 33,554,432 B
    u16* t2 = (u16*)(ws + 100663296);           // 8192*64*2   =  1,048,576 B
    u16* B2 = (u16*)(ws + 101711872);           // 4096*64*2   =    524,288 B

    prep_kernel<<<10240, 256, 0, stream>>>(qw, scales, lora_B, x, lora_A,
                                           Wb, B2, xb, t2);
    qlora_gemm<<<dim3(512), 512, 0, stream>>>(xb, Wb, t2, B2, out);
}

// Round 18
// 310.401 us; speedup vs baseline: 1.0138x; 1.0138x over previous
//
#include <hip/hip_runtime.h>
#include <hip/hip_bf16.h>

// QLoRA forward: out = x @ dequant(q_w, scales)^T + 2.0 * (x @ A^T) @ B^T
// M=8192, N=4096, K=4096, rank=16, group=64.
// Round 18: r16 verbatim MINUS s_setprio in the GEMM (T5 is null-to-negative
// on lockstep non-phase-split GEMMs, m190: all 8 waves of the 1 resident
// block are barrier-locked in the same phase -> nothing to arbitrate).
// r17's split-mfma1 (235us, -5%) reverted. Everything else = r16 (311.3us
// best: GEMM 222-227us x4 reproductions, prep ~60us).

typedef unsigned short u16;
typedef __attribute__((ext_vector_type(8))) short bf16x8;
typedef __attribute__((ext_vector_type(4))) float f32x4;
typedef __attribute__((ext_vector_type(4))) int i32x4;

#define M_DIM 8192
#define N_DIM 4096
#define K_DIM 4096
#define BK 64
#define KT_MAIN 64
#define NT 65

// round-to-nearest-even f32 -> bf16
__device__ static inline u16 f2bf(float f) {
    union { float f; unsigned u; } v; v.f = f;
    unsigned r = v.u + 0x7fffu + ((v.u >> 16) & 1u);
    return (u16)(r >> 16);
}

__device__ static inline void gload16(const void* g, void* s) {
    __builtin_amdgcn_global_load_lds(
        (const __attribute__((address_space(1))) void*)g,
        (__attribute__((address_space(3))) void*)s, 16, 0, 0);
}

// ---------------- fused prep (r13/r16 layout) -------------------------------
// blocks 0..1023: xprep (2 rows/wave); 1024..9215: wprep; 9216..10239: bprep.
// t2 [8192][64] bf16 (cols 16..63 = 0); B2 [4096][64] (cols 16..63 = 0).
__global__ __launch_bounds__(256) void prep_kernel(
        const int* __restrict__ q, const float* __restrict__ scales,
        const float* __restrict__ lora_B, const float* __restrict__ x,
        const float* __restrict__ lora_A,
        u16* __restrict__ Wb, u16* __restrict__ B2,
        u16* __restrict__ xb, u16* __restrict__ t2) {
    const int tid = threadIdx.x;
    int b = blockIdx.x;
    if (b < 1024) {
        // ---- xprep: xb = bf16(x); t2 = bf16(2 * x @ A^T), [8192][64] ----
        const int w = tid >> 6, l = tid & 63;
        const int rb = b * 8 + w * 2;
        float acc[2][16];
#pragma unroll
        for (int j = 0; j < 2; ++j)
#pragma unroll
            for (int r = 0; r < 16; ++r) acc[j][r] = 0.f;

        for (int i = 0; i < 16; ++i) {
            int k0 = i * 256 + l * 4;
            f32x4 x0 = __builtin_nontemporal_load(
                            (const f32x4*)&x[(size_t)rb * K_DIM + k0]);
            f32x4 x1 = __builtin_nontemporal_load(
                            (const f32x4*)&x[(size_t)(rb + 1) * K_DIM + k0]);
            ushort4 o0, o1;
            o0.x = f2bf(x0.x); o0.y = f2bf(x0.y); o0.z = f2bf(x0.z); o0.w = f2bf(x0.w);
            o1.x = f2bf(x1.x); o1.y = f2bf(x1.y); o1.z = f2bf(x1.z); o1.w = f2bf(x1.w);
            *(ushort4*)&xb[(size_t)rb * K_DIM + k0]       = o0;
            *(ushort4*)&xb[(size_t)(rb + 1) * K_DIM + k0] = o1;
#pragma unroll
            for (int r = 0; r < 16; ++r) {
                f32x4 av = *(const f32x4*)&lora_A[(size_t)r * K_DIM + k0];
                acc[0][r] += x0.x * av.x + x0.y * av.y + x0.z * av.z + x0.w * av.w;
                acc[1][r] += x1.x * av.x + x1.y * av.y + x1.z * av.z + x1.w * av.w;
            }
        }
#pragma unroll
        for (int j = 0; j < 2; ++j)
#pragma unroll
            for (int r = 0; r < 16; ++r) {
                float v = acc[j][r];
                v += __shfl_xor(v, 32); v += __shfl_xor(v, 16);
                v += __shfl_xor(v, 8);  v += __shfl_xor(v, 4);
                v += __shfl_xor(v, 2);  v += __shfl_xor(v, 1);
                acc[j][r] = v;
            }
        // lane l -> row rb+(l>>5), col pair (l&31): pack 2 bf16 per dword.
        float lo = 0.f, hi = 0.f;
#pragma unroll
        for (int j = 0; j < 2; ++j)
#pragma unroll
            for (int c = 0; c < 8; ++c)
                if (l == j * 32 + c) { lo = acc[j][2 * c]; hi = acc[j][2 * c + 1]; }
        unsigned pack = (unsigned)f2bf(2.0f * lo) | ((unsigned)f2bf(2.0f * hi) << 16);
        *(unsigned*)&t2[(size_t)(rb + (l >> 5)) * 64 + (l & 31) * 2] = pack;
    } else if (b < 9216) {
        // ---- wprep: Wb[o][k] = bf16(q[o][k] * scales[o][k/64]) ----
        int idx = (b - 1024) * 256 + tid;
        int o  = idx >> 9;
        int kc = (idx & 511) << 3;
        float s = scales[(o << 6) + (kc >> 6)];
        const i32x4* qp = (const i32x4*)(q + (size_t)o * K_DIM + kc);
        i32x4 q0 = __builtin_nontemporal_load(qp);
        i32x4 q1 = __builtin_nontemporal_load(qp + 1);
        ushort4 r0, r1;
        r0.x = f2bf((float)q0.x * s); r0.y = f2bf((float)q0.y * s);
        r0.z = f2bf((float)q0.z * s); r0.w = f2bf((float)q0.w * s);
        r1.x = f2bf((float)q1.x * s); r1.y = f2bf((float)q1.y * s);
        r1.z = f2bf((float)q1.z * s); r1.w = f2bf((float)q1.w * s);
        *(ushort4*)&Wb[(size_t)o * K_DIM + kc]     = r0;
        *(ushort4*)&Wb[(size_t)o * K_DIM + kc + 4] = r1;
    } else {
        // ---- bprep: B2 [4096][64], cols 16..63 = 0 ----
        int idx = (b - 9216) * 256 + tid;   // 1024 blocks -> 4096*64
        int o = idx >> 6, r = idx & 63;
        B2[idx] = (r < 16) ? f2bf(lora_B[o * 16 + r]) : (u16)0;
    }
}

// ---------------- main GEMM (r10/r16 structure, setprio removed) -----------
// 256x256 tile, BK=64, 8 waves (2x4), LDS 2 bufs x (A 32KB + B 32KB) = 128KB.
// Row = 128B = 8 slots of 16B. Swizzle: phys slot p of row r holds logical
// slot p ^ (r&7); achieved by pre-swizzling the gload SOURCE (dest linear).
__global__ __launch_bounds__(512, 2) void qlora_gemm(
        const u16* __restrict__ xb, const u16* __restrict__ Wb,
        const u16* __restrict__ t2, const u16* __restrict__ B2,
        float* __restrict__ out) {
    __shared__ u16 lds[2][32768];                 // 128 KB
    // XCD map: XCD x owns 16bm x 4bn rectangle (bijective, 512 = 8*64).
    int bid = blockIdx.x;
    int x8 = bid & 7, sq = bid >> 3;
    int bm = (x8 & 1) * 16 + (sq & 15);           // 0..31
    int bn = (x8 >> 1) * 4 + (sq >> 4);           // 0..15
    const int tid = threadIdx.x, w = tid >> 6, l = tid & 63;
    const int wr = w >> 2, wc = w & 3;            // 2x4 wave grid, 128x64/wave
    const int fr = l & 15, fq = l >> 4;
    const int s0 = fq ^ (fr & 7);                 // swizzled slot, kk=0 (kk1: ^4)

    const int sw16 = ((l & 7) ^ ((l >> 3) & 7)) << 4;   // pre-swizzled src offset
    const int rl   = w * 8 + (l >> 3);
    const int rA0  = bm * 256 + rl;
    const int rB0  = bn * 256 + rl;
    char* ldsC = (char*)&lds[0][0];
    const int dst = w * 1024 + l * 16;            // + o*8192 (A), +32768 (B)

    const int arow = (wr * 128 + fr) * 128;              // + i*2048 + slot*16
    const int brow = 32768 + (wc * 64 + fr) * 128;       // + j*2048 + slot*16

    f32x4 acc[8][4] = {};
    bf16x8 a0[8], b0[4], a1[8], b1[4];

    auto stage = [&](int kt, int buf) {           // 8 gloads: full 64KB tile
        char* base = ldsC + buf * 65536;
        if (kt < KT_MAIN) {
            size_t ko = (size_t)kt * 128;
#pragma unroll
            for (int o = 0; o < 4; ++o) {
                gload16((const char*)xb + ((size_t)(rA0 + o * 64) * 8192 + sw16) + ko,
                        base + dst + o * 8192);
                gload16((const char*)Wb + ((size_t)(rB0 + o * 64) * 8192 + sw16) + ko,
                        base + 32768 + dst + o * 8192);
            }
        } else {                                  // lora tile: 128B rows
#pragma unroll
            for (int o = 0; o < 4; ++o) {
                gload16((const char*)t2 + ((size_t)(rA0 + o * 64) * 128 + sw16),
                        base + dst + o * 8192);
                gload16((const char*)B2 + ((size_t)(rB0 + o * 64) * 128 + sw16),
                        base + 32768 + dst + o * 8192);
            }
        }
    };

    auto read0 = [&](const char* cb) {
#pragma unroll
        for (int j = 0; j < 4; ++j)
            b0[j] = *(const bf16x8*)(cb + brow + j * 2048 + s0 * 16);
#pragma unroll
        for (int i = 0; i < 8; ++i)
            a0[i] = *(const bf16x8*)(cb + arow + i * 2048 + s0 * 16);
    };
    auto read1 = [&](const char* cb) {
#pragma unroll
        for (int j = 0; j < 4; ++j)
            b1[j] = *(const bf16x8*)(cb + brow + j * 2048 + (s0 ^ 4) * 16);
#pragma unroll
        for (int i = 0; i < 8; ++i)
            a1[i] = *(const bf16x8*)(cb + arow + i * 2048 + (s0 ^ 4) * 16);
    };
    auto mfma0 = [&]() {
#pragma unroll
        for (int i = 0; i < 8; ++i)
#pragma unroll
            for (int j = 0; j < 4; ++j)
                acc[i][j] = __builtin_amdgcn_mfma_f32_16x16x32_bf16(
                                a0[i], b0[j], acc[i][j], 0, 0, 0);
    };
    auto mfma1 = [&]() {
#pragma unroll
        for (int i = 0; i < 8; ++i)
#pragma unroll
            for (int j = 0; j < 4; ++j)
                acc[i][j] = __builtin_amdgcn_mfma_f32_16x16x32_bf16(
                                a1[i], b1[j], acc[i][j], 0, 0, 0);
    };

    // ---------------- prologue ----------------
    stage(0, 0);
    asm volatile("s_waitcnt vmcnt(0)" ::: "memory");
    __builtin_amdgcn_s_barrier();
    asm volatile("" ::: "memory");

    read0(ldsC);

    for (int t = 0; t < NT; ++t) {
        const char* cb = ldsC + (t & 1) * 65536;

        // (1) kk1 frag reads — drain under kk0 MFMA
        read1(cb);
        // (2) next-tile staging — lands under this tile's compute
        if (t + 1 < NT) stage(t + 1, (t + 1) & 1);
        __builtin_amdgcn_sched_barrier(0);

        // (3) MFMA kk0 (a0/b0 long-landed; compiler waits their lgkm)
        mfma0();
        __builtin_amdgcn_sched_barrier(0);

        // (4) protocol: buf-reads drained + next tile staged, then rendezvous
        asm volatile("s_waitcnt lgkmcnt(0)" ::: "memory");
        asm volatile("s_waitcnt vmcnt(0)" ::: "memory");
        __builtin_amdgcn_s_barrier();
        asm volatile("" ::: "memory");

        // (5) next-tile kk0 frag reads — drain under kk1 MFMA
        if (t + 1 < NT) {
            const char* nb = ldsC + ((t + 1) & 1) * 65536;
            read0(nb);
        }
        __builtin_amdgcn_sched_barrier(0);

        // (6) MFMA kk1
        mfma1();
        __builtin_amdgcn_sched_barrier(0);
    }

    // epilogue: C/D layout col=lane&15, row=(lane>>4)*4+reg  [validated]
    float* obase = out + (size_t)(bm * 256 + wr * 128 + fq * 4) * N_DIM
                       + bn * 256 + wc * 64 + fr;
#pragma unroll
    for (int i = 0; i < 8; ++i)
#pragma unroll
        for (int j = 0; j < 4; ++j)
#pragma unroll
            for (int r = 0; r < 4; ++r)
                obase[(size_t)(i * 16 + r) * N_DIM + j * 16] = acc[i][j][r];
}

extern "C" void kernel_launch(void* const* d_in, const int* in_sizes, int n_in,
                              void* d_out, int out_size, void* d_ws, size_t ws_size,
                              hipStream_t stream) {
    const float* x      = (const float*)d_in[0];
    const int*   qw     = (const int*)d_in[1];
    const float* scales = (const float*)d_in[2];
    const float* lora_A = (const float*)d_in[3];
    const float* lora_B = (const float*)d_in[4];
    float* out = (float*)d_out;

    char* ws = (char*)d_ws;
    u16* xb = (u16*)(ws);                       // 8192*4096*2 = 67,108,864 B
    u16* Wb = (u16*)(ws + 67108864);            // 4096*4096*2 = 33,554,432 B
    u16* t2 = (u16*)(ws + 100663296);           // 8192*64*2   =  1,048,576 B
    u16* B2 = (u16*)(ws + 101711872);           // 4096*64*2   =    524,288 B

    prep_kernel<<<10240, 256, 0, stream>>>(qw, scales, lora_B, x, lora_A,
                                           Wb, B2, xb, t2);
    qlora_gemm<<<dim3(512), 512, 0, stream>>>(xb, Wb, t2, B2, out);
}